// Round 1
// baseline (274.642 us; speedup 1.0000x reference)
//
#include <hip/hip_runtime.h>
#include <hip/hip_bf16.h>
#include <math.h>

// Problem constants
#define BDIM   128   // batch
#define N_NODES 512  // nodes per graph
#define KNB    10    // neighbors
#define FDIM   128   // feature dim
#define KDIM   256   // concat dim = 2*F
#define CDIM   40    // classes

// ---------------------------------------------------------------------------
// Transpose w_sage (L, G=128, K=256) -> wt (L, K=256, G=128) so the GEMM's
// LDS staging is stride-1 (conflict-free writes, coalesced reads).
// ---------------------------------------------------------------------------
__global__ __launch_bounds__(256) void transpose_w_kernel(
    const float* __restrict__ w, float* __restrict__ wt)
{
    int idx = blockIdx.x * 256 + threadIdx.x;   // 2*256*128 = 65536 total
    int l   = idx >> 15;
    int rem = idx & 32767;
    int f   = rem >> 7;     // 0..255 (k index)
    int g   = rem & 127;    // 0..127 (output feature)
    wt[idx] = w[l * 32768 + g * 256 + f];
}

// ---------------------------------------------------------------------------
// Fused SAGE layer: gather-mean + concat staged to LDS, then tiled fp32 GEMM.
// Block computes 32 rows x all 128 output features.
//   bshift = 9 for layer 0 (row m -> b=m>>9, n=m&511), 0 for layer 1
//            (row m -> b=m, n=0; only n==0 rows are consumed downstream).
// ---------------------------------------------------------------------------
__global__ __launch_bounds__(256) void sage_layer_kernel(
    const float* __restrict__ hin,    // (B, N, F)
    const int*   __restrict__ neigh,  // (B, N, K)
    const float* __restrict__ wt,     // (KDIM, FDIM) transposed weights, this layer
    const float* __restrict__ bias,   // (FDIM)
    float*       __restrict__ hout,   // (rows, FDIM)
    int bshift)
{
    __shared__ float cat[32][KDIM];   // 32 KB: [row][k]  (k-contiguous)
    __shared__ float wl[64][FDIM];    // 32 KB: [k][g]    (g-contiguous)

    const int tid   = threadIdx.x;
    const int m0    = blockIdx.x * 32;
    const int nmask = (1 << bshift) - 1;

    // ---- stage cat tile: mp (k 0..127) and self h (k 128..255) ----
    {
        const int f     = tid & 127;
        const int rhalf = tid >> 7;           // 0 or 1
        for (int it = 0; it < 16; ++it) {
            int r = it * 2 + rhalf;           // 0..31
            int m = m0 + r;
            int b = m >> bshift;
            int n = m & nmask;
            const int*   nb = neigh + ((b * N_NODES + n) * KNB);
            const float* hb = hin + (size_t)b * (N_NODES * FDIM);
            float s = 0.f;
            #pragma unroll
            for (int k = 0; k < KNB; ++k) {
                int j = nb[k];
                s += hb[j * FDIM + f];
            }
            cat[r][f]        = s * 0.1f;      // mean over K=10
            cat[r][FDIM + f] = hb[n * FDIM + f];
        }
    }

    // ---- GEMM: 4 rows x 4 g per thread, K in 4 chunks of 64 ----
    float4 acc[4];
    acc[0] = make_float4(0.f, 0.f, 0.f, 0.f);
    acc[1] = acc[0]; acc[2] = acc[0]; acc[3] = acc[0];
    const int rg  = tid >> 5;    // 0..7  -> rows rg*4 .. rg*4+3
    const int cg  = tid & 31;    // 0..31 -> g = cg*4 .. cg*4+3
    const int rg4 = rg * 4;
    const int cg4 = cg * 4;

    for (int kc = 0; kc < 4; ++kc) {
        __syncthreads();   // cat ready (kc=0) / previous wl reads done
        #pragma unroll
        for (int i = 0; i < 32; ++i) {
            int idx = i * 256 + tid;
            ((float*)wl)[idx] = wt[kc * 64 * FDIM + idx];
        }
        __syncthreads();
        const int kbase = kc * 64;
        #pragma unroll
        for (int k = 0; k < 64; k += 4) {
            float4 w0 = *(const float4*)&wl[k + 0][cg4];
            float4 w1 = *(const float4*)&wl[k + 1][cg4];
            float4 w2 = *(const float4*)&wl[k + 2][cg4];
            float4 w3 = *(const float4*)&wl[k + 3][cg4];
            #pragma unroll
            for (int r = 0; r < 4; ++r) {
                float4 a = *(const float4*)&cat[rg4 + r][kbase + k];
                acc[r].x = fmaf(a.x, w0.x, acc[r].x);
                acc[r].x = fmaf(a.y, w1.x, acc[r].x);
                acc[r].x = fmaf(a.z, w2.x, acc[r].x);
                acc[r].x = fmaf(a.w, w3.x, acc[r].x);
                acc[r].y = fmaf(a.x, w0.y, acc[r].y);
                acc[r].y = fmaf(a.y, w1.y, acc[r].y);
                acc[r].y = fmaf(a.z, w2.y, acc[r].y);
                acc[r].y = fmaf(a.w, w3.y, acc[r].y);
                acc[r].z = fmaf(a.x, w0.z, acc[r].z);
                acc[r].z = fmaf(a.y, w1.z, acc[r].z);
                acc[r].z = fmaf(a.z, w2.z, acc[r].z);
                acc[r].z = fmaf(a.w, w3.z, acc[r].z);
                acc[r].w = fmaf(a.x, w0.w, acc[r].w);
                acc[r].w = fmaf(a.y, w1.w, acc[r].w);
                acc[r].w = fmaf(a.z, w2.w, acc[r].w);
                acc[r].w = fmaf(a.w, w3.w, acc[r].w);
            }
        }
    }

    // ---- epilogue: bias + store ----
    float4 bv = *(const float4*)&bias[cg4];
    #pragma unroll
    for (int r = 0; r < 4; ++r) {
        int m = m0 + rg4 + r;
        float4 o;
        o.x = acc[r].x + bv.x;
        o.y = acc[r].y + bv.y;
        o.z = acc[r].z + bv.z;
        o.w = acc[r].w + bv.w;
        *(float4*)&hout[(size_t)m * FDIM + cg4] = o;
    }
}

// ---------------------------------------------------------------------------
// z = h2 @ lin1_w^T + lin1_b   (128 x 64)
// ---------------------------------------------------------------------------
__global__ __launch_bounds__(64) void lin1_kernel(
    const float* __restrict__ h2,     // (128, 128)
    const float* __restrict__ w1,     // (64, 128)
    const float* __restrict__ b1,     // (64)
    float*       __restrict__ z)      // (128, 64)
{
    int b = blockIdx.x;
    int j = threadIdx.x;
    const float4* h4 = (const float4*)(h2 + b * FDIM);
    const float4* w4 = (const float4*)(w1 + j * FDIM);
    float4 s4 = make_float4(0.f, 0.f, 0.f, 0.f);
    #pragma unroll
    for (int f = 0; f < 32; ++f) {
        float4 a = h4[f];
        float4 w = w4[f];
        s4.x = fmaf(a.x, w.x, s4.x);
        s4.y = fmaf(a.y, w.y, s4.y);
        s4.z = fmaf(a.z, w.z, s4.z);
        s4.w = fmaf(a.w, w.w, s4.w);
    }
    z[b * 64 + j] = s4.x + s4.y + s4.z + s4.w + b1[j];
}

// ---------------------------------------------------------------------------
// BatchNorm (over batch axis) + ReLU + lin2 + softmax. Single block.
// ---------------------------------------------------------------------------
__global__ __launch_bounds__(128) void head_kernel(
    const float* __restrict__ z,      // (128, 64)
    const float* __restrict__ gamma,  // (64)
    const float* __restrict__ beta,   // (64)
    const float* __restrict__ w2,     // (40, 64)
    const float* __restrict__ b2,     // (40)
    float*       __restrict__ out)    // (128, 40)
{
    __shared__ float zs[128][65];     // +1 pad: column AND row access conflict-free
    __shared__ float sc[64], sh[64];
    const int tid = threadIdx.x;

    // load z
    for (int i = 0; i < 64; ++i) {
        int idx = i * 128 + tid;
        zs[idx >> 6][idx & 63] = z[idx];
    }
    __syncthreads();

    // per-feature batch stats
    if (tid < 64) {
        float s = 0.f, ss = 0.f;
        for (int i = 0; i < 128; ++i) {
            float v = zs[i][tid];
            s += v; ss += v * v;
        }
        float mu  = s * (1.f / 128.f);
        float var = ss * (1.f / 128.f) - mu * mu;
        float rs  = rsqrtf(var + 1e-5f) * gamma[tid];
        sc[tid] = rs;
        sh[tid] = beta[tid] - mu * rs;
    }
    __syncthreads();

    // normalize + relu
    {
        int j = tid & 63;
        for (int i = tid >> 6; i < 128; i += 2) {
            float v = fmaf(zs[i][j], sc[j], sh[j]);
            zs[i][j] = fmaxf(v, 0.f);
        }
    }
    __syncthreads();

    // logits + softmax, one batch row per thread
    {
        int i = tid;
        float lg[CDIM];
        float mx = -1e30f;
        #pragma unroll 4
        for (int c = 0; c < CDIM; ++c) {
            const float* w = w2 + c * 64;
            float s = b2[c];
            for (int f = 0; f < 64; ++f) s = fmaf(zs[i][f], w[f], s);
            lg[c] = s;
            mx = fmaxf(mx, s);
        }
        float den = 0.f;
        for (int c = 0; c < CDIM; ++c) {
            lg[c] = __expf(lg[c] - mx);
            den += lg[c];
        }
        float inv = 1.f / den;
        for (int c = 0; c < CDIM; ++c) out[i * CDIM + c] = lg[c] * inv;
    }
}

// ---------------------------------------------------------------------------
extern "C" void kernel_launch(void* const* d_in, const int* in_sizes, int n_in,
                              void* d_out, int out_size, void* d_ws, size_t ws_size,
                              hipStream_t stream)
{
    const float* x      = (const float*)d_in[0];   // (128, 512, 128)
    const int*   neigh  = (const int*)  d_in[1];   // (128, 512, 10)
    const float* w_sage = (const float*)d_in[2];   // (2, 128, 256)
    const float* b_sage = (const float*)d_in[3];   // (2, 128)
    const float* lin1_w = (const float*)d_in[4];   // (64, 128)
    const float* lin1_b = (const float*)d_in[5];   // (64)
    const float* bn_g   = (const float*)d_in[6];   // (64)
    const float* bn_b   = (const float*)d_in[7];   // (64)
    const float* lin2_w = (const float*)d_in[8];   // (40, 64)
    const float* lin2_b = (const float*)d_in[9];   // (40)
    float* out = (float*)d_out;                    // (128, 40)

    // workspace layout (floats)
    float* wt = (float*)d_ws;          // 2*256*128      = 65536
    float* h1 = wt + 65536;            // 128*512*128    = 8388608
    float* h2 = h1 + 8388608;          // 128*128        = 16384
    float* z  = h2 + 16384;            // 128*64         = 8192

    // 1) transpose sage weights to [k][g]
    transpose_w_kernel<<<256, 256, 0, stream>>>(w_sage, wt);

    // 2) layer 0: all 65536 rows
    sage_layer_kernel<<<65536 / 32, 256, 0, stream>>>(x, neigh, wt, b_sage, h1, 9);

    // 3) layer 1: only n==0 rows are consumed downstream -> 128 rows
    sage_layer_kernel<<<128 / 32, 256, 0, stream>>>(h1, neigh, wt + 32768,
                                                    b_sage + 128, h2, 0);

    // 4) head
    lin1_kernel<<<128, 64, 0, stream>>>(h2, lin1_w, lin1_b, z);
    head_kernel<<<1, 128, 0, stream>>>(z, bn_g, bn_b, lin2_w, lin2_b, out);
}

// Round 2
// 175.191 us; speedup vs baseline: 1.5677x; 1.5677x over previous
//
#include <hip/hip_runtime.h>
#include <hip/hip_bf16.h>
#include <math.h>

// Problem constants
#define BDIM    128   // batch graphs
#define N_NODES 512
#define KNB     10
#define FDIM    128
#define CDIM    40

// ---------------------------------------------------------------------------
// ALGEBRAIC COLLAPSE: both SAGE layers are affine (no activation) and only
// h[:,0,:] is consumed. With A_l = w_sage[l][:, :128] (mp half),
// B_l = w_sage[l][:, 128:] (self half), L1 = lin1_w:
//   z[b] = gconst + G1·(0.01·v1) + Gc·(0.1·v2) + G4·v4
//   G1 = L1·A2·A1, Gc = L1·(A2·B1 + B2·A1), G4 = L1·B2·B1
//   gconst = lin1_b + L1·b1 + L1·(A2+B2)·b0
//   v1[b] = Σ_{k<10,j<10} x[b, neigh[b, nb_k, j]]   (nb_k = neigh[b,0,k])
//   v2[b] = Σ_{k<10} x[b, nb_k]      (note: mp-of-node-0 set == same set)
//   v4[b] = x[b, 0]
// Then BatchNorm(batch) + ReLU + lin2 + softmax in the head kernel.
// ---------------------------------------------------------------------------

// K1: T1 = L1·A2, T2 = L1·B2   (each 64x128, row-major). grid 64 x 256.
__global__ __launch_bounds__(256) void precompute_T(
    const float* __restrict__ lin1_w,   // (64,128)
    const float* __restrict__ w_sage,   // (2,128,256)
    float* __restrict__ T)              // T1[0..8191], T2[8192..16383]
{
    int idx   = blockIdx.x * 256 + threadIdx.x;   // 16384
    int which = idx >> 13;                        // 0: A2, 1: B2
    int rem   = idx & 8191;
    int j     = rem >> 7;
    int g     = rem & 127;
    const float* w2l = w_sage + 32768;            // layer-1 weights
    float acc = 0.f;
    #pragma unroll 4
    for (int g2 = 0; g2 < 128; ++g2)
        acc = fmaf(lin1_w[j * 128 + g2], w2l[g2 * 256 + which * 128 + g], acc);
    T[idx] = acc;
}

// K2: G matrices (stored TRANSPOSED: G[which][f*64+j]) + gconst. grid 97 x 256.
__global__ __launch_bounds__(256) void precompute_G(
    const float* __restrict__ w_sage,
    const float* __restrict__ T,
    const float* __restrict__ b_sage,   // (2,128): b0 = [0..127], b1 = [128..255]
    const float* __restrict__ lin1_w,
    const float* __restrict__ lin1_b,
    float* __restrict__ G,              // 3 x 8192, transposed [f][j]
    float* __restrict__ gconst)         // (64)
{
    const float* T1 = T;
    const float* T2 = T + 8192;
    int bx = blockIdx.x;
    if (bx < 96) {
        int idx   = bx * 256 + threadIdx.x;       // 24576
        int which = idx / 8192;                   // block-uniform (8192 = 32 blocks)
        int rem   = idx & 8191;
        int j     = rem >> 7;
        int f     = rem & 127;
        float acc = 0.f;
        #pragma unroll 4
        for (int g = 0; g < 128; ++g) {
            float a1 = w_sage[g * 256 + f];        // A1[g][f]
            float b1 = w_sage[g * 256 + 128 + f];  // B1[g][f]
            float t1 = T1[j * 128 + g];
            float t2 = T2[j * 128 + g];
            if (which == 0)      acc = fmaf(t1, a1, acc);
            else if (which == 1) { acc = fmaf(t1, b1, acc); acc = fmaf(t2, a1, acc); }
            else                 acc = fmaf(t2, b1, acc);
        }
        G[which * 8192 + f * 64 + j] = acc;
    } else if (threadIdx.x < 64) {
        int j = threadIdx.x;
        float acc = lin1_b[j];
        for (int g2 = 0; g2 < 128; ++g2)
            acc = fmaf(lin1_w[j * 128 + g2], b_sage[128 + g2], acc);   // L1·b1
        for (int g = 0; g < 128; ++g)
            acc = fmaf(T1[j * 128 + g] + T2[j * 128 + g], b_sage[g], acc); // (T1+T2)·b0
        gconst[j] = acc;
    }
}

// K3: per-graph aggregation (v1,v2,v4) + z = G·v + gconst. grid 128 x 256.
__global__ __launch_bounds__(256) void aggregate_z(
    const float* __restrict__ x,       // (128,512,128)
    const int*   __restrict__ neigh,   // (128,512,10)
    const float* __restrict__ G,
    const float* __restrict__ gconst,
    float* __restrict__ z)             // (128,64)
{
    __shared__ int   nb0s[16];
    __shared__ int   l2s[112];
    __shared__ float pA[2][128], pB[2][128];
    __shared__ float vs[3][128];

    const int b   = blockIdx.x;
    const int tid = threadIdx.x;
    const int* nbB = neigh + b * (N_NODES * KNB);

    if (tid < 10) nb0s[tid] = nbB[tid];           // neigh[b,0,:]
    __syncthreads();
    if (tid < 100) {
        int k = tid / 10, jj = tid - k * 10;
        l2s[tid] = nbB[nb0s[k] * KNB + jj];       // neigh[b, nb_k, jj]
    }
    __syncthreads();

    const int f = tid & 127;
    const int h = tid >> 7;
    const float* xb = x + (size_t)b * (N_NODES * FDIM);

    float s1 = 0.f, s2 = 0.f;
    #pragma unroll 5
    for (int t = h * 50; t < h * 50 + 50; ++t) s1 += xb[l2s[t] * FDIM + f];
    #pragma unroll
    for (int k = h * 5; k < h * 5 + 5; ++k)    s2 += xb[nb0s[k] * FDIM + f];
    pA[h][f] = s1;
    pB[h][f] = s2;
    __syncthreads();

    if (tid < 128) {
        vs[0][f] = (pA[0][f] + pA[1][f]) * 0.01f;   // 0.01·v1
        vs[1][f] = (pB[0][f] + pB[1][f]) * 0.1f;    // 0.1·v2
        vs[2][f] = xb[f];                            // v4 = x[b,0,:]
    }
    __syncthreads();

    if (tid < 64) {
        const int j = tid;
        const float* G1 = G;
        const float* Gc = G + 8192;
        const float* G4 = G + 16384;
        float acc = gconst[j];
        #pragma unroll 4
        for (int ff = 0; ff < 128; ++ff) {
            acc = fmaf(G1[ff * 64 + j], vs[0][ff], acc);
            acc = fmaf(Gc[ff * 64 + j], vs[1][ff], acc);
            acc = fmaf(G4[ff * 64 + j], vs[2][ff], acc);
        }
        z[b * 64 + j] = acc;
    }
}

// K4: BatchNorm (over batch) + ReLU + lin2 + softmax. Single block. (verified R1)
__global__ __launch_bounds__(128) void head_kernel(
    const float* __restrict__ z,      // (128, 64)
    const float* __restrict__ gamma,  // (64)
    const float* __restrict__ beta,   // (64)
    const float* __restrict__ w2,     // (40, 64)
    const float* __restrict__ b2,     // (40)
    float*       __restrict__ out)    // (128, 40)
{
    __shared__ float zs[128][65];
    __shared__ float sc[64], sh[64];
    const int tid = threadIdx.x;

    for (int i = 0; i < 64; ++i) {
        int idx = i * 128 + tid;
        zs[idx >> 6][idx & 63] = z[idx];
    }
    __syncthreads();

    if (tid < 64) {
        float s = 0.f, ss = 0.f;
        for (int i = 0; i < 128; ++i) {
            float v = zs[i][tid];
            s += v; ss += v * v;
        }
        float mu  = s * (1.f / 128.f);
        float var = ss * (1.f / 128.f) - mu * mu;
        float rs  = rsqrtf(var + 1e-5f) * gamma[tid];
        sc[tid] = rs;
        sh[tid] = beta[tid] - mu * rs;
    }
    __syncthreads();

    {
        int j = tid & 63;
        for (int i = tid >> 6; i < 128; i += 2) {
            float v = fmaf(zs[i][j], sc[j], sh[j]);
            zs[i][j] = fmaxf(v, 0.f);
        }
    }
    __syncthreads();

    {
        int i = tid;
        float lg[CDIM];
        float mx = -1e30f;
        #pragma unroll 4
        for (int c = 0; c < CDIM; ++c) {
            const float* w = w2 + c * 64;
            float s = b2[c];
            for (int f = 0; f < 64; ++f) s = fmaf(zs[i][f], w[f], s);
            lg[c] = s;
            mx = fmaxf(mx, s);
        }
        float den = 0.f;
        for (int c = 0; c < CDIM; ++c) {
            lg[c] = __expf(lg[c] - mx);
            den += lg[c];
        }
        float inv = 1.f / den;
        for (int c = 0; c < CDIM; ++c) out[i * CDIM + c] = lg[c] * inv;
    }
}

// ---------------------------------------------------------------------------
extern "C" void kernel_launch(void* const* d_in, const int* in_sizes, int n_in,
                              void* d_out, int out_size, void* d_ws, size_t ws_size,
                              hipStream_t stream)
{
    const float* x      = (const float*)d_in[0];
    const int*   neigh  = (const int*)  d_in[1];
    const float* w_sage = (const float*)d_in[2];
    const float* b_sage = (const float*)d_in[3];
    const float* lin1_w = (const float*)d_in[4];
    const float* lin1_b = (const float*)d_in[5];
    const float* bn_g   = (const float*)d_in[6];
    const float* bn_b   = (const float*)d_in[7];
    const float* lin2_w = (const float*)d_in[8];
    const float* lin2_b = (const float*)d_in[9];
    float* out = (float*)d_out;

    // workspace (floats): T 16384 | G 24576 | gconst 64 | z 8192  (~200 KB)
    float* T      = (float*)d_ws;
    float* G      = T + 16384;
    float* gconst = G + 24576;
    float* z      = gconst + 64;

    precompute_T<<<64, 256, 0, stream>>>(lin1_w, w_sage, T);
    precompute_G<<<97, 256, 0, stream>>>(w_sage, T, b_sage, lin1_w, lin1_b, G, gconst);
    aggregate_z <<<BDIM, 256, 0, stream>>>(x, neigh, G, gconst, z);
    head_kernel <<<1, 128, 0, stream>>>(z, bn_g, bn_b, lin2_w, lin2_b, out);
}

// Round 3
// 126.939 us; speedup vs baseline: 2.1636x; 1.3801x over previous
//
#include <hip/hip_runtime.h>
#include <hip/hip_bf16.h>
#include <math.h>

// Problem constants
#define BDIM    128   // batch graphs
#define N_NODES 512
#define KNB     10
#define FDIM    128
#define CDIM    40

// ---------------------------------------------------------------------------
// ALGEBRA (verified on-HW in R2, absmax 0.0): both SAGE layers are affine and
// only h[:,0,:] is consumed. With A_l/B_l = mp/self halves of w_sage[l]:
//   v1[b] = sum_{k,j} x[b, neigh[b, nb_k, j]]   (nb_k = neigh[b,0,k])
//   v2[b] = sum_k x[b, nb_k]     (mp-of-node-0 index set both layers)
//   v4[b] = x[b,0]
//   p = A1·(0.01v1) + B1·(0.1v2) + b0        (= mean_k h1[nb_k])
//   q = A1·(0.1v2)  + B1·v4      + b0        (= h1[0])
//   r = A2·p + B2·q + b1                     (= h2[0])
//   z = L1·r + lin1_b
// R3 change: apply factors right-to-left PER GRAPH (128-way parallel, weights
// L2-broadcast) instead of precomputing G=L1·A2·A1 (latency-bound serial
// dispatch chain: 50.8us at 0.44% VALUBusy in R2). 2 dispatches total.
// ---------------------------------------------------------------------------

__global__ __launch_bounds__(256) void fused_z(
    const float* __restrict__ x,       // (128,512,128)
    const int*   __restrict__ neigh,   // (128,512,10)
    const float* __restrict__ w_sage,  // (2,128,256)
    const float* __restrict__ b_sage,  // (2,128)
    const float* __restrict__ lin1_w,  // (64,128)
    const float* __restrict__ lin1_b,  // (64)
    float*       __restrict__ z)       // (128,64)
{
    __shared__ int   nb0s[16];
    __shared__ int   l2s[112];
    __shared__ float part[2][2][128];   // reused scratch across stages
    __shared__ float vs0[128], vs1[128], vs2[128];
    __shared__ float pv[128], qv[128], rv[128];
    __shared__ float zpart[4][64];

    const int b   = blockIdx.x;
    const int tid = threadIdx.x;
    const int* nbB = neigh + b * (N_NODES * KNB);

    // ---- stage 0: 2-hop index lists ----
    if (tid < 10) nb0s[tid] = nbB[tid];                 // neigh[b,0,:]
    __syncthreads();
    if (tid < 100) {
        int k = tid / 10, jj = tid - k * 10;
        l2s[tid] = nbB[nb0s[k] * KNB + jj];             // neigh[b, nb_k, jj]
    }
    __syncthreads();

    // ---- stage 1: gather-sum v1, v2, v4 ----
    const int f = tid & 127;
    const int h = tid >> 7;
    const float* xb = x + (size_t)b * (N_NODES * FDIM);
    {
        float s1 = 0.f, s2 = 0.f;
        #pragma unroll 10
        for (int t = h * 50; t < h * 50 + 50; ++t) s1 += xb[l2s[t] * FDIM + f];
        #pragma unroll
        for (int k = h * 5; k < h * 5 + 5; ++k)    s2 += xb[nb0s[k] * FDIM + f];
        part[0][h][f] = s1;
        part[1][h][f] = s2;
    }
    __syncthreads();
    if (h == 0) {
        vs0[f] = (part[0][0][f] + part[0][1][f]) * 0.01f;   // 0.01*v1
        vs1[f] = (part[1][0][f] + part[1][1][f]) * 0.1f;    // 0.1*v2
        vs2[f] = xb[f];                                     // v4
    }
    __syncthreads();

    // ---- stage 2: p = A1*vs0 + B1*vs1, q = A1*vs1 + B1*vs2 ----
    // thread (g, half): row g of w_sage layer 0, f-range [half*64, half*64+64)
    {
        const int g = tid & 127, half = tid >> 7;
        const float4* w4 = (const float4*)(w_sage + g * 256);
        float p0 = 0.f, p1 = 0.f, q0 = 0.f, q1 = 0.f;
        #pragma unroll
        for (int i = 0; i < 16; ++i) {
            int f4 = half * 16 + i;          // A1 segment
            float4 w = w4[f4];
            int fb = f4 * 4;
            p0 = fmaf(w.x, vs0[fb + 0], p0); p1 = fmaf(w.y, vs0[fb + 1], p1);
            p0 = fmaf(w.z, vs0[fb + 2], p0); p1 = fmaf(w.w, vs0[fb + 3], p1);
            q0 = fmaf(w.x, vs1[fb + 0], q0); q1 = fmaf(w.y, vs1[fb + 1], q1);
            q0 = fmaf(w.z, vs1[fb + 2], q0); q1 = fmaf(w.w, vs1[fb + 3], q1);
        }
        #pragma unroll
        for (int i = 0; i < 16; ++i) {
            int f4 = 32 + half * 16 + i;     // B1 segment
            float4 w = w4[f4];
            int fb = (f4 - 32) * 4;
            p0 = fmaf(w.x, vs1[fb + 0], p0); p1 = fmaf(w.y, vs1[fb + 1], p1);
            p0 = fmaf(w.z, vs1[fb + 2], p0); p1 = fmaf(w.w, vs1[fb + 3], p1);
            q0 = fmaf(w.x, vs2[fb + 0], q0); q1 = fmaf(w.y, vs2[fb + 1], q1);
            q0 = fmaf(w.z, vs2[fb + 2], q0); q1 = fmaf(w.w, vs2[fb + 3], q1);
        }
        part[0][half][g] = p0 + p1;
        part[1][half][g] = q0 + q1;
    }
    __syncthreads();
    if (h == 0) {
        float b0 = b_sage[f];
        pv[f] = part[0][0][f] + part[0][1][f] + b0;
        qv[f] = part[1][0][f] + part[1][1][f] + b0;
    }
    __syncthreads();

    // ---- stage 3: r = A2*p + B2*q + b1 ----
    {
        const int g2 = tid & 127, half = tid >> 7;
        const float4* w4 = (const float4*)(w_sage + 32768 + g2 * 256 + half * 128);
        const float* vv = half ? qv : pv;
        float a0 = 0.f, a1 = 0.f;
        #pragma unroll
        for (int i = 0; i < 32; ++i) {
            float4 w = w4[i];
            int gb = i * 4;
            a0 = fmaf(w.x, vv[gb + 0], a0); a1 = fmaf(w.y, vv[gb + 1], a1);
            a0 = fmaf(w.z, vv[gb + 2], a0); a1 = fmaf(w.w, vv[gb + 3], a1);
        }
        part[0][half][g2] = a0 + a1;
    }
    __syncthreads();
    if (h == 0) rv[f] = b_sage[128 + f] + part[0][0][f] + part[0][1][f];
    __syncthreads();

    // ---- stage 4: z = L1*r + lin1_b ----
    {
        const int j = tid & 63, qt = tid >> 6;
        const float4* w4 = (const float4*)(lin1_w + j * 128 + qt * 32);
        float a0 = 0.f, a1 = 0.f;
        #pragma unroll
        for (int i = 0; i < 8; ++i) {
            float4 w = w4[i];
            int gb = qt * 32 + i * 4;
            a0 = fmaf(w.x, rv[gb + 0], a0); a1 = fmaf(w.y, rv[gb + 1], a1);
            a0 = fmaf(w.z, rv[gb + 2], a0); a1 = fmaf(w.w, rv[gb + 3], a1);
        }
        zpart[qt][j] = a0 + a1;
    }
    __syncthreads();
    if (tid < 64)
        z[b * 64 + tid] = lin1_b[tid] + zpart[0][tid] + zpart[1][tid]
                        + zpart[2][tid] + zpart[3][tid];
}

// ---------------------------------------------------------------------------
// BatchNorm (over batch) + ReLU + lin2 + softmax. Single block. (verified R1)
// ---------------------------------------------------------------------------
__global__ __launch_bounds__(128) void head_kernel(
    const float* __restrict__ z,      // (128, 64)
    const float* __restrict__ gamma,  // (64)
    const float* __restrict__ beta,   // (64)
    const float* __restrict__ w2,     // (40, 64)
    const float* __restrict__ b2,     // (40)
    float*       __restrict__ out)    // (128, 40)
{
    __shared__ float zs[128][65];
    __shared__ float sc[64], sh[64];
    const int tid = threadIdx.x;

    for (int i = 0; i < 64; ++i) {
        int idx = i * 128 + tid;
        zs[idx >> 6][idx & 63] = z[idx];
    }
    __syncthreads();

    if (tid < 64) {
        float s = 0.f, ss = 0.f;
        for (int i = 0; i < 128; ++i) {
            float v = zs[i][tid];
            s += v; ss += v * v;
        }
        float mu  = s * (1.f / 128.f);
        float var = ss * (1.f / 128.f) - mu * mu;
        float rs  = rsqrtf(var + 1e-5f) * gamma[tid];
        sc[tid] = rs;
        sh[tid] = beta[tid] - mu * rs;
    }
    __syncthreads();

    {
        int j = tid & 63;
        for (int i = tid >> 6; i < 128; i += 2) {
            float v = fmaf(zs[i][j], sc[j], sh[j]);
            zs[i][j] = fmaxf(v, 0.f);
        }
    }
    __syncthreads();

    {
        int i = tid;
        float lg[CDIM];
        float mx = -1e30f;
        #pragma unroll 4
        for (int c = 0; c < CDIM; ++c) {
            const float* w = w2 + c * 64;
            float s = b2[c];
            for (int f = 0; f < 64; ++f) s = fmaf(zs[i][f], w[f], s);
            lg[c] = s;
            mx = fmaxf(mx, s);
        }
        float den = 0.f;
        for (int c = 0; c < CDIM; ++c) {
            lg[c] = __expf(lg[c] - mx);
            den += lg[c];
        }
        float inv = 1.f / den;
        for (int c = 0; c < CDIM; ++c) out[i * CDIM + c] = lg[c] * inv;
    }
}

// ---------------------------------------------------------------------------
extern "C" void kernel_launch(void* const* d_in, const int* in_sizes, int n_in,
                              void* d_out, int out_size, void* d_ws, size_t ws_size,
                              hipStream_t stream)
{
    const float* x      = (const float*)d_in[0];
    const int*   neigh  = (const int*)  d_in[1];
    const float* w_sage = (const float*)d_in[2];
    const float* b_sage = (const float*)d_in[3];
    const float* lin1_w = (const float*)d_in[4];
    const float* lin1_b = (const float*)d_in[5];
    const float* bn_g   = (const float*)d_in[6];
    const float* bn_b   = (const float*)d_in[7];
    const float* lin2_w = (const float*)d_in[8];
    const float* lin2_b = (const float*)d_in[9];
    float* out = (float*)d_out;

    float* z = (float*)d_ws;   // 128*64 floats

    fused_z    <<<BDIM, 256, 0, stream>>>(x, neigh, w_sage, b_sage,
                                          lin1_w, lin1_b, z);
    head_kernel<<<1, 128, 0, stream>>>(z, bn_g, bn_b, lin2_w, lin2_b, out);
}